// Round 3
// baseline (2826.824 us; speedup 1.0000x reference)
//
#include <hip/hip_runtime.h>
#include <hip/hip_bf16.h>

#define EPSN 1e-12f

// Problem dims (fixed by setup_inputs)
#define BB   8
#define NN   1024
#define DIN  384
#define DOUT 384
#define SS   128
#define PP   128

// Main-kernel tiling
#define NBLK 64   // tokens per block (one per lane)
#define DBLK 8    // d per block (2 per wave)
#define CCH  16   // c chunk staged in LDS

// ---------------------------------------------------------------------------
// Kernel 1: wn[s][p] = scale * maps_weight[s][p] / max(||maps_weight[s]||, eps)
// ---------------------------------------------------------------------------
__global__ void wnorm_kernel(const float* __restrict__ mw,
                             const float* __restrict__ scale,
                             float* __restrict__ wn) {
    __shared__ float row[PP];
    const int s = blockIdx.x;
    const int t = threadIdx.x;
    row[t] = mw[s * PP + t];
    __syncthreads();
    float ss = 0.f;
#pragma unroll
    for (int p = 0; p < PP; ++p) ss = fmaf(row[p], row[p], ss);
    const float nrm = fmaxf(sqrtf(ss), EPSN);
    wn[s * PP + t] = scale[0] * row[t] / nrm;
}

// ---------------------------------------------------------------------------
// Kernel 2: coef[n][s] = softmax_s( dot(l2norm(pe[n]), wn[s]) )
// ---------------------------------------------------------------------------
__global__ void coef_kernel(const float* __restrict__ pe,
                            const float* __restrict__ wn,
                            float* __restrict__ coef) {
    __shared__ float pen[PP];
    __shared__ float red[SS];
    const int n = blockIdx.x;
    const int t = threadIdx.x;
    pen[t] = pe[n * PP + t];
    __syncthreads();
    float ss = 0.f;
#pragma unroll
    for (int p = 0; p < PP; ++p) ss = fmaf(pen[p], pen[p], ss);
    const float rn = 1.0f / fmaxf(sqrtf(ss), EPSN);

    const float* wrow = wn + t * PP;
    float lg = 0.f;
#pragma unroll
    for (int p = 0; p < PP; ++p) lg = fmaf(pen[p], wrow[p], lg);
    lg *= rn;

    red[t] = lg;
    __syncthreads();
    for (int off = 64; off > 0; off >>= 1) {
        if (t < off) red[t] = fmaxf(red[t], red[t + off]);
        __syncthreads();
    }
    const float m = red[0];
    __syncthreads();
    const float e = expf(lg - m);
    red[t] = e;
    __syncthreads();
    for (int off = 64; off > 0; off >>= 1) {
        if (t < off) red[t] += red[t + off];
        __syncthreads();
    }
    coef[n * SS + t] = e / red[0];
}

// ---------------------------------------------------------------------------
// Kernel 3 (main, fused combine+apply), spill-free restructure:
//   - coef tile in LDS (XOR-swizzled, conflict-free ds_read_b128)
//   - 2 d per wave, 8-c-wide chains: 64 combine FMA per cf quad
//   - x tile in LDS [b][g][n^(g<<1)] (write AND read conflict-free)
//   - weight rows wave-uniform (readfirstlane d) -> scalar-load path
// ---------------------------------------------------------------------------

// cf quad accessor: float4 at lane row `ln`, s-quad `q` (0..31), swizzled
#define CFQ(base, ln, q) \
    (*reinterpret_cast<const float4*>((base) + ((ln) << 7) + ((((q) ^ ((ln) & 7))) << 2)))

__global__ __launch_bounds__(256, 2) void topo_main_kernel(
    const float* __restrict__ x,
    const float* __restrict__ weight,
    const float* __restrict__ bias,
    const float* __restrict__ coef,
    float* __restrict__ out) {
    __shared__ float4 xld[BB][CCH / 4][NBLK];   // 32 KiB, n-index XOR-swizzled by g<<1
    __shared__ float  cfl[NBLK * SS];           // 32 KiB, 16B-slot swizzle byte^((row&7)<<4)

    const int tid  = threadIdx.x;
    const int lane = tid & 63;
    const int wid  = tid >> 6;

    // bijective XCD-chunked swizzle: 768 blocks, 8 XCDs, 96 each.
    // XCD owns 6 consecutive dgrps x all 16 ngrps, ngrp-fastest.
    const int beta = blockIdx.x;           // 0..767
    const int xcd  = beta & 7;
    const int slot = beta >> 3;            // 0..95
    const int dgrp = xcd * 6 + (slot >> 4);
    const int ngrp = slot & 15;

    const int N0 = ngrp * NBLK;
    const int n  = N0 + lane;
    const int d0 = __builtin_amdgcn_readfirstlane(dgrp * DBLK + wid * 2);

    // ---- stage coef tile into LDS (swizzled), coalesced global reads ----
#pragma unroll
    for (int k = 0; k < 8; ++k) {
        const int e   = k * 256 + tid;
        const int row = e >> 5;            // 0..63
        const int q   = e & 31;            // 0..31
        const float4 v = *reinterpret_cast<const float4*>(
            coef + (size_t)(N0 + row) * SS + q * 4);
        *reinterpret_cast<float4*>(cfl + (row << 7) + ((q ^ (row & 7)) << 2)) = v;
    }

    // ---- x staging assignment: g = tid&3, n-slot = tid>>2 ----
    const int sg = tid & 3;
    const int sn = (tid >> 2) & 63;
    const float* xstage = x + ((size_t)N0 + sn) * DIN + sg * 4;

    float4 xreg[BB];
#pragma unroll
    for (int b = 0; b < BB; ++b)
        xreg[b] = *reinterpret_cast<const float4*>(xstage + (size_t)b * NN * DIN);

    float acc0[BB], acc1[BB];
#pragma unroll
    for (int b = 0; b < BB; ++b) { acc0[b] = 0.f; acc1[b] = 0.f; }

    const float* wbase0 = weight + (size_t)d0 * (DIN * SS);
    const float* wbase1 = wbase0 + (size_t)DIN * SS;

    for (int c0 = 0; c0 < DIN; c0 += CCH) {
        __syncthreads();   // includes coef-tile readiness on first iteration
#pragma unroll
        for (int b = 0; b < BB; ++b) xld[b][sg][sn ^ (sg << 1)] = xreg[b];
        __syncthreads();

        if (c0 + CCH < DIN) {
#pragma unroll
            for (int b = 0; b < BB; ++b)
                xreg[b] = *reinterpret_cast<const float4*>(
                    xstage + (size_t)b * NN * DIN + (c0 + CCH));
        }

#pragma unroll
        for (int half = 0; half < 2; ++half) {
            const int cbase = c0 + half * 8;
            float wv0[8], wv1[8];
#pragma unroll
            for (int cc = 0; cc < 8; ++cc) { wv0[cc] = 0.f; wv1[cc] = 0.f; }

            const float* wr0 = wbase0 + (size_t)cbase * SS;
            const float* wr1 = wbase1 + (size_t)cbase * SS;

            for (int so = 0; so < 16; ++so) {      // s-octets
                const int s0 = so * 8;
                const float4 ca = CFQ(cfl, lane, so * 2);
                const float4 cb = CFQ(cfl, lane, so * 2 + 1);
                float cs[8];
                cs[0] = ca.x; cs[1] = ca.y; cs[2] = ca.z; cs[3] = ca.w;
                cs[4] = cb.x; cs[5] = cb.y; cs[6] = cb.z; cs[7] = cb.w;
#pragma unroll
                for (int cc = 0; cc < 8; ++cc) {
                    const float* wa = wr0 + cc * SS + s0;   // wave-uniform
                    const float* wb = wr1 + cc * SS + s0;
#pragma unroll
                    for (int j = 0; j < 8; ++j) {
                        wv0[cc] = fmaf(cs[j], wa[j], wv0[cc]);
                        wv1[cc] = fmaf(cs[j], wb[j], wv1[cc]);
                    }
                }
            }

            // apply to the 8 batch rows
            const int g0 = half * 2, g1 = half * 2 + 1;
#pragma unroll
            for (int b = 0; b < BB; ++b) {
                const float4 xa = xld[b][g0][lane ^ (g0 << 1)];
                const float4 xb = xld[b][g1][lane ^ (g1 << 1)];
                acc0[b] = fmaf(xa.x, wv0[0], acc0[b]);
                acc0[b] = fmaf(xa.y, wv0[1], acc0[b]);
                acc0[b] = fmaf(xa.z, wv0[2], acc0[b]);
                acc0[b] = fmaf(xa.w, wv0[3], acc0[b]);
                acc0[b] = fmaf(xb.x, wv0[4], acc0[b]);
                acc0[b] = fmaf(xb.y, wv0[5], acc0[b]);
                acc0[b] = fmaf(xb.z, wv0[6], acc0[b]);
                acc0[b] = fmaf(xb.w, wv0[7], acc0[b]);
                acc1[b] = fmaf(xa.x, wv1[0], acc1[b]);
                acc1[b] = fmaf(xa.y, wv1[1], acc1[b]);
                acc1[b] = fmaf(xa.z, wv1[2], acc1[b]);
                acc1[b] = fmaf(xa.w, wv1[3], acc1[b]);
                acc1[b] = fmaf(xb.x, wv1[4], acc1[b]);
                acc1[b] = fmaf(xb.y, wv1[5], acc1[b]);
                acc1[b] = fmaf(xb.z, wv1[6], acc1[b]);
                acc1[b] = fmaf(xb.w, wv1[7], acc1[b]);
            }
        }
    }

    // ---- bias epilogue (cf from LDS, bias rows wave-uniform) ----
    const float* br0 = bias + (size_t)d0 * SS;
    const float* br1 = br0 + SS;
    float bd0 = 0.f, bd1 = 0.f;
#pragma unroll
    for (int sq = 0; sq < 32; ++sq) {
        const float4 cq = CFQ(cfl, lane, sq);
        const int s0 = sq * 4;
        bd0 = fmaf(cq.x, br0[s0 + 0], bd0);
        bd0 = fmaf(cq.y, br0[s0 + 1], bd0);
        bd0 = fmaf(cq.z, br0[s0 + 2], bd0);
        bd0 = fmaf(cq.w, br0[s0 + 3], bd0);
        bd1 = fmaf(cq.x, br1[s0 + 0], bd1);
        bd1 = fmaf(cq.y, br1[s0 + 1], bd1);
        bd1 = fmaf(cq.z, br1[s0 + 2], bd1);
        bd1 = fmaf(cq.w, br1[s0 + 3], bd1);
    }

#pragma unroll
    for (int b = 0; b < BB; ++b) {
        out[((size_t)b * NN + n) * DOUT + d0]     = acc0[b] + bd0;
        out[((size_t)b * NN + n) * DOUT + d0 + 1] = acc1[b] + bd1;
    }
}

// ---------------------------------------------------------------------------
extern "C" void kernel_launch(void* const* d_in, const int* in_sizes, int n_in,
                              void* d_out, int out_size, void* d_ws, size_t ws_size,
                              hipStream_t stream) {
    const float* x     = (const float*)d_in[0];   // (8,1024,384)
    const float* pe    = (const float*)d_in[1];   // (1024,128)
    const float* mw    = (const float*)d_in[2];   // (128,128)
    const float* scale = (const float*)d_in[3];   // ()
    const float* wgt   = (const float*)d_in[4];   // (384,384,128)
    const float* bias  = (const float*)d_in[5];   // (384,128)
    float* out = (float*)d_out;

    float* wn   = (float*)d_ws;                   // 64 KiB
    float* coef = wn + SS * PP;                   // 512 KiB

    wnorm_kernel<<<dim3(SS), dim3(PP), 0, stream>>>(mw, scale, wn);
    coef_kernel<<<dim3(NN), dim3(PP), 0, stream>>>(pe, wn, coef);
    // 768 blocks = (384/8 dgrps) x 16 ngrps, swizzled in-kernel
    topo_main_kernel<<<dim3((DOUT / DBLK) * (NN / NBLK)), dim3(256), 0, stream>>>(
        x, wgt, bias, coef, out);
}

// Round 5
// 278.653 us; speedup vs baseline: 10.1446x; 10.1446x over previous
//
#include <hip/hip_runtime.h>
#include <hip/hip_bf16.h>

#define EPSN 1e-12f

// Problem dims
#define BB   8
#define NN   1024
#define DIN  384
#define DOUT 384
#define SS   128
#define PP   128

typedef __attribute__((ext_vector_type(8))) short bf16x8;
typedef __attribute__((ext_vector_type(4))) float f32x4;

__device__ __forceinline__ float bf2f(unsigned short u) {
    union { unsigned int i; float f; } v; v.i = ((unsigned int)u) << 16; return v.f;
}

// ---------------------------------------------------------------------------
// prep 1: wn[s][p] = scale * l2norm(maps_weight)[s][p]
// ---------------------------------------------------------------------------
__global__ void wnorm_kernel(const float* __restrict__ mw,
                             const float* __restrict__ scale,
                             float* __restrict__ wn) {
    __shared__ float row[PP];
    const int s = blockIdx.x, t = threadIdx.x;
    row[t] = mw[s * PP + t];
    __syncthreads();
    float ss = 0.f;
#pragma unroll
    for (int p = 0; p < PP; ++p) ss = fmaf(row[p], row[p], ss);
    wn[s * PP + t] = scale[0] * row[t] / fmaxf(sqrtf(ss), EPSN);
}

// ---------------------------------------------------------------------------
// prep 2: coef[n][s] = softmax_s(l2norm(pe[n]) . wn[s]); writes f32 + bf16
// ---------------------------------------------------------------------------
__global__ void coef_kernel(const float* __restrict__ pe,
                            const float* __restrict__ wn,
                            float* __restrict__ coef,
                            __hip_bfloat16* __restrict__ coefbf) {
    __shared__ float pen[PP];
    __shared__ float red[SS];
    const int n = blockIdx.x, t = threadIdx.x;
    pen[t] = pe[n * PP + t];
    __syncthreads();
    float ss = 0.f;
#pragma unroll
    for (int p = 0; p < PP; ++p) ss = fmaf(pen[p], pen[p], ss);
    const float rn = 1.0f / fmaxf(sqrtf(ss), EPSN);
    const float* wrow = wn + t * PP;
    float lg = 0.f;
#pragma unroll
    for (int p = 0; p < PP; ++p) lg = fmaf(pen[p], wrow[p], lg);
    lg *= rn;
    red[t] = lg;
    __syncthreads();
    for (int off = 64; off > 0; off >>= 1) {
        if (t < off) red[t] = fmaxf(red[t], red[t + off]);
        __syncthreads();
    }
    const float m = red[0];
    __syncthreads();
    const float e = expf(lg - m);
    red[t] = e;
    __syncthreads();
    for (int off = 64; off > 0; off >>= 1) {
        if (t < off) red[t] += red[t + off];
        __syncthreads();
    }
    const float cv = e / red[0];
    coef[n * SS + t] = cv;
    coefbf[n * SS + t] = __float2bfloat16(cv);
}

// ---------------------------------------------------------------------------
// prep 3: bvec[n][d] = coef[n] . bias[d]   (exact f32)
// ---------------------------------------------------------------------------
__global__ void bvec_kernel(const float* __restrict__ coef,
                            const float* __restrict__ bias,
                            float* __restrict__ bvec) {
    __shared__ float cr[SS];
    const int n = blockIdx.x, t = threadIdx.x;
    if (t < SS) cr[t] = coef[n * SS + t];
    __syncthreads();
    const float* br = bias + (size_t)t * SS;
    float s = 0.f;
#pragma unroll
    for (int p = 0; p < SS; ++p) s = fmaf(cr[p], br[p], s);
    bvec[(size_t)n * DOUT + t] = s;
}

// ---------------------------------------------------------------------------
// prep 4: wfrag = weight rearranged into per-lane MFMA A-fragments (bf16).
// Layout: [dblk 96][cq 96][kt 4][lane 64] x 8 bf16.
// A-frag row m = l15: (c_sub = l15>>2, d_sub = l15&3); k = kt*32 + g*8 + j.
// ---------------------------------------------------------------------------
__global__ void wfrag_prep(const float* __restrict__ weight,
                           __hip_bfloat16* __restrict__ wfrag) {
    const int id = blockIdx.x * 256 + threadIdx.x;    // 0..2359295
    const int lane = id & 63;
    const int kt = (id >> 6) & 3;
    const int rem = id >> 8;                          // dblk*96 + cq
    const int cq = rem % 96;
    const int dblk = rem / 96;
    const int l15 = lane & 15, g = lane >> 4;
    const int d = dblk * 4 + (l15 & 3);
    const int c = cq * 4 + (l15 >> 2);
    const int s0 = kt * 32 + g * 8;
    const float* src = weight + ((size_t)d * DIN + c) * SS + s0;
    __hip_bfloat16* dst = wfrag + (size_t)id * 8;
#pragma unroll
    for (int j = 0; j < 8; ++j) dst[j] = __float2bfloat16(src[j]);
}

// ---------------------------------------------------------------------------
// prep 5: xfrag[((ngrp*2+nhalf)*96 + cq)*2 + nt][lane = g*16+l15] x 8 bf16
// holds x[b][n = ngrp*64+nhalf*32+nt*16+l15][c = cq*4+g] for b=0..7.
// ---------------------------------------------------------------------------
__global__ void xfrag_prep(const float* __restrict__ x,
                           __hip_bfloat16* __restrict__ xfrag) {
    const int id = blockIdx.x * 256 + threadIdx.x;    // n*384 + c
    const int n = id / DIN, c = id % DIN;
    const int ngrp = n >> 6, nhalf = (n >> 5) & 1, nt = (n >> 4) & 1, l15 = n & 15;
    const int cq = c >> 2, g = c & 3;
    const size_t G = (((size_t)ngrp * 2 + nhalf) * 96 + cq) * 2 + nt;
    __hip_bfloat16* dst = xfrag + (G * 64 + (g * 16 + l15)) * 8;
#pragma unroll
    for (int b = 0; b < BB; ++b)
        dst[b] = __float2bfloat16(x[((size_t)b * NN + n) * DIN + c]);
}

// ---------------------------------------------------------------------------
// MAIN: fused combine(MFMA bf16, W stays f32 in C-frags) + apply(VALU f32).
// Block = 128 threads = 2 waves = 2 n-halves. Wave = 32 tokens x 8 d x FULL c
// (full c per wave => no cross-wave reduction, fixes round-4 race).
// 768 blocks = 48 dgrp x 16 ngrp, XCD-chunked bijective swizzle.
// ---------------------------------------------------------------------------
__global__ __launch_bounds__(128, 2) void topo_mfma_kernel(
    const __hip_bfloat16* __restrict__ wfrag,
    const __hip_bfloat16* __restrict__ xfrag,
    const __hip_bfloat16* __restrict__ coefbf,
    const float* __restrict__ bvec,
    float* __restrict__ out) {
    const int tid   = threadIdx.x;
    const int lane  = tid & 63;
    const int nhalf = tid >> 6;          // wave id = n-half
    const int l15   = lane & 15;
    const int g     = lane >> 4;

    const int bid  = blockIdx.x;
    const int wg   = (bid & 7) * 96 + (bid >> 3);   // bijective, 768 = 8*96
    const int dgrp = wg >> 4;                       // 0..47  (8 d each)
    const int ngrp = wg & 15;                       // 0..15  (64 n each)

    // coef B-fragments (col = l15 -> token), register-resident
    bf16x8 cf[2][4];
#pragma unroll
    for (int nt = 0; nt < 2; ++nt) {
        const int n = ngrp * 64 + nhalf * 32 + nt * 16 + l15;
#pragma unroll
        for (int kt = 0; kt < 4; ++kt)
            cf[nt][kt] = *reinterpret_cast<const bf16x8*>(coefbf + n * SS + kt * 32 + g * 8);
    }

    f32x4 acc[2][2][BB];   // [nt][dq][b], components = d_sub 0..3
#pragma unroll
    for (int nt = 0; nt < 2; ++nt)
#pragma unroll
        for (int dq = 0; dq < 2; ++dq)
#pragma unroll
            for (int b = 0; b < BB; ++b) acc[nt][dq][b] = (f32x4){0.f, 0.f, 0.f, 0.f};

    const size_t xgbase = ((size_t)ngrp * 2 + nhalf) * 96;

    for (int cq = 0; cq < 96; ++cq) {
        // x fragments: lane holds 8 b's at (n from l15, c = cq*4 + g)
        bf16x8 xf[2];
#pragma unroll
        for (int nt = 0; nt < 2; ++nt)
            xf[nt] = *reinterpret_cast<const bf16x8*>(
                xfrag + (((xgbase + cq) * 2 + nt) * 64 + lane) * 8);

#pragma unroll
        for (int dq = 0; dq < 2; ++dq) {
            const int dblk = dgrp * 2 + dq;
            const bf16x8* ab = reinterpret_cast<const bf16x8*>(wfrag) +
                               ((size_t)(dblk * 96 + cq) * 4) * 64 + lane;
            const bf16x8 af0 = ab[0];
            const bf16x8 af1 = ab[64];
            const bf16x8 af2 = ab[128];
            const bf16x8 af3 = ab[192];
#pragma unroll
            for (int nt = 0; nt < 2; ++nt) {
                f32x4 wq = (f32x4){0.f, 0.f, 0.f, 0.f};
                wq = __builtin_amdgcn_mfma_f32_16x16x32_bf16(af0, cf[nt][0], wq, 0, 0, 0);
                wq = __builtin_amdgcn_mfma_f32_16x16x32_bf16(af1, cf[nt][1], wq, 0, 0, 0);
                wq = __builtin_amdgcn_mfma_f32_16x16x32_bf16(af2, cf[nt][2], wq, 0, 0, 0);
                wq = __builtin_amdgcn_mfma_f32_16x16x32_bf16(af3, cf[nt][3], wq, 0, 0, 0);
                // wq[r] = W[n = base+l15][d = dblk*4+r][c = cq*4+g]
#pragma unroll
                for (int b = 0; b < BB; ++b) {
                    const float xb = bf2f((unsigned short)xf[nt][b]);
                    acc[nt][dq][b] += wq * xb;
                }
            }
        }
    }

    // epilogue: reduce the 4 c-phases (lane groups g) and store out + bvec
#pragma unroll
    for (int nt = 0; nt < 2; ++nt) {
        const int n = ngrp * 64 + nhalf * 32 + nt * 16 + l15;
#pragma unroll
        for (int dq = 0; dq < 2; ++dq) {
            const int dbase = dgrp * 8 + dq * 4;
            const f32x4 bv = *reinterpret_cast<const f32x4*>(bvec + (size_t)n * DOUT + dbase);
#pragma unroll
            for (int b = 0; b < BB; ++b) {
                f32x4 a = acc[nt][dq][b];
#pragma unroll
                for (int r = 0; r < 4; ++r) {
                    float v = a[r];
                    v += __shfl_xor(v, 16);
                    v += __shfl_xor(v, 32);
                    a[r] = v;
                }
                if ((b >> 1) == g) {   // one writer per (b,n,d-quad)
                    *reinterpret_cast<f32x4*>(out + ((size_t)b * NN + n) * DOUT + dbase) = a + bv;
                }
            }
        }
    }
}

// ---------------------------------------------------------------------------
extern "C" void kernel_launch(void* const* d_in, const int* in_sizes, int n_in,
                              void* d_out, int out_size, void* d_ws, size_t ws_size,
                              hipStream_t stream) {
    const float* x     = (const float*)d_in[0];   // (8,1024,384)
    const float* pe    = (const float*)d_in[1];   // (1024,128)
    const float* mw    = (const float*)d_in[2];   // (128,128)
    const float* scale = (const float*)d_in[3];   // ()
    const float* wgt   = (const float*)d_in[4];   // (384,384,128)
    const float* bias  = (const float*)d_in[5];   // (384,128)
    float* out = (float*)d_out;

    char* ws = (char*)d_ws;
    float*          wn     = (float*)(ws + 0);                 //  64 KiB
    float*          coef   = (float*)(ws + 65536);             // 512 KiB
    __hip_bfloat16* coefbf = (__hip_bfloat16*)(ws + 589824);   // 256 KiB
    float*          bvec   = (float*)(ws + 851968);            // 1.5 MiB
    __hip_bfloat16* xfrag  = (__hip_bfloat16*)(ws + 2424832);  // 6.0 MiB
    __hip_bfloat16* wfrag  = (__hip_bfloat16*)(ws + 8716288);  // 36 MiB

    wnorm_kernel<<<dim3(SS), dim3(PP), 0, stream>>>(mw, scale, wn);
    coef_kernel<<<dim3(NN), dim3(PP), 0, stream>>>(pe, wn, coef, coefbf);
    bvec_kernel<<<dim3(NN), dim3(DOUT), 0, stream>>>(coef, bias, bvec);
    xfrag_prep<<<dim3((NN * DIN) / 256), dim3(256), 0, stream>>>(x, xfrag);
    wfrag_prep<<<dim3((96 * 96 * 4 * 64) / 256), dim3(256), 0, stream>>>(wgt, wfrag);
    topo_mfma_kernel<<<dim3(768), dim3(128), 0, stream>>>(wfrag, xfrag, coefbf, bvec, out);
}

// Round 6
// 225.266 us; speedup vs baseline: 12.5488x; 1.2370x over previous
//
#include <hip/hip_runtime.h>
#include <hip/hip_bf16.h>

#define EPSN 1e-12f

// Problem dims
#define BB   8
#define NN   1024
#define DIN  384
#define DOUT 384
#define SS   128
#define PP   128

#define NCQ  97   // 96 weight c-quads + 1 bias (homogeneous) quad

typedef __attribute__((ext_vector_type(8))) short bf16x8;
typedef __attribute__((ext_vector_type(4))) float f32x4;

__device__ __forceinline__ float bf2f(unsigned short u) {
    union { unsigned int i; float f; } v; v.i = ((unsigned int)u) << 16; return v.f;
}

// ---------------------------------------------------------------------------
// prep 1: wnT[p][s] = scale * l2norm(maps_weight)[s][p]  (TRANSPOSED output
// so coef_kernel's inner loop reads coalesced)
// ---------------------------------------------------------------------------
__global__ void wnorm_kernel(const float* __restrict__ mw,
                             const float* __restrict__ scale,
                             float* __restrict__ wnT) {
    __shared__ float row[PP];
    const int s = blockIdx.x, t = threadIdx.x;
    row[t] = mw[s * PP + t];
    __syncthreads();
    float ss = 0.f;
#pragma unroll
    for (int p = 0; p < PP; ++p) ss = fmaf(row[p], row[p], ss);
    wnT[t * SS + s] = scale[0] * row[t] / fmaxf(sqrtf(ss), EPSN);
}

// ---------------------------------------------------------------------------
// prep 2: coefbf[n][s] = bf16(softmax_s(l2norm(pe[n]) . wn[s]))
// inner loop now reads wnT[p][t]: lane-consecutive -> coalesced
// ---------------------------------------------------------------------------
__global__ void coef_kernel(const float* __restrict__ pe,
                            const float* __restrict__ wnT,
                            __hip_bfloat16* __restrict__ coefbf) {
    __shared__ float pen[PP];
    __shared__ float red[SS];
    const int n = blockIdx.x, t = threadIdx.x;
    pen[t] = pe[n * PP + t];
    __syncthreads();
    float ss = 0.f;
#pragma unroll
    for (int p = 0; p < PP; ++p) ss = fmaf(pen[p], pen[p], ss);
    const float rn = 1.0f / fmaxf(sqrtf(ss), EPSN);
    float lg = 0.f;
#pragma unroll
    for (int p = 0; p < PP; ++p) lg = fmaf(pen[p], wnT[p * SS + t], lg);
    lg *= rn;
    red[t] = lg;
    __syncthreads();
    for (int off = 64; off > 0; off >>= 1) {
        if (t < off) red[t] = fmaxf(red[t], red[t + off]);
        __syncthreads();
    }
    const float m = red[0];
    __syncthreads();
    const float e = expf(lg - m);
    red[t] = e;
    __syncthreads();
    for (int off = 64; off > 0; off >>= 1) {
        if (t < off) red[t] += red[t + off];
        __syncthreads();
    }
    coefbf[n * SS + t] = __float2bfloat16(e / red[0]);
}

// ---------------------------------------------------------------------------
// prep 3: wfrag = weight (+ bias as c-quad 96) as per-lane MFMA A-fragments.
// Layout: [dblk 96][cq 97][kt 4][lane 64] x 8 bf16.
// A-row m = l15: (c_sub = l15>>2, d_sub = l15&3); k = kt*32 + g*8 + j.
// cq==96: c_sub==0 -> bias[d][s], c_sub>0 -> 0   (homogeneous coordinate)
// ---------------------------------------------------------------------------
__global__ void wfrag_prep(const float* __restrict__ weight,
                           const float* __restrict__ bias,
                           __hip_bfloat16* __restrict__ wfrag) {
    const int id = blockIdx.x * 256 + threadIdx.x;    // 96*97*4*64 = 2,383,872
    const int lane = id & 63;
    const int kt = (id >> 6) & 3;
    const int rem = id >> 8;                          // dblk*97 + cq
    const int cq = rem % NCQ;
    const int dblk = rem / NCQ;
    const int l15 = lane & 15, g = lane >> 4;
    const int d = dblk * 4 + (l15 & 3);
    const int s0 = kt * 32 + g * 8;
    __hip_bfloat16* dst = wfrag + (size_t)id * 8;
    if (cq < 96) {
        const int c = cq * 4 + (l15 >> 2);
        const float* src = weight + ((size_t)d * DIN + c) * SS + s0;
#pragma unroll
        for (int j = 0; j < 8; ++j) dst[j] = __float2bfloat16(src[j]);
    } else if ((l15 >> 2) == 0) {
        const float* src = bias + (size_t)d * SS + s0;
#pragma unroll
        for (int j = 0; j < 8; ++j) dst[j] = __float2bfloat16(src[j]);
    } else {
#pragma unroll
        for (int j = 0; j < 8; ++j) dst[j] = __float2bfloat16(0.f);
    }
}

// ---------------------------------------------------------------------------
// prep 4: xfrag[((ngrp*2+nhalf)*97 + cq)*2 + nt][lane = g*16+l15] x 8 bf16
// holds x[b][n][c=cq*4+g]; cq==96 pad: 1.0 at c==384 (g==0), else 0.
// ---------------------------------------------------------------------------
__global__ void xfrag_prep(const float* __restrict__ x,
                           __hip_bfloat16* __restrict__ xfrag) {
    const int id = blockIdx.x * 256 + threadIdx.x;    // n*388 + cc ; total 397,312
    const int n = id / 388, cc = id % 388;
    const int ngrp = n >> 6, nhalf = (n >> 5) & 1, nt = (n >> 4) & 1, l15 = n & 15;
    const int cq = cc >> 2, g = cc & 3;
    const size_t G = (((size_t)ngrp * 2 + nhalf) * NCQ + cq) * 2 + nt;
    __hip_bfloat16* dst = xfrag + (G * 64 + (g * 16 + l15)) * 8;
    if (cc < 384) {
#pragma unroll
        for (int b = 0; b < BB; ++b)
            dst[b] = __float2bfloat16(x[((size_t)b * NN + n) * DIN + cc]);
    } else {
        const __hip_bfloat16 v = __float2bfloat16(cc == 384 ? 1.0f : 0.0f);
#pragma unroll
        for (int b = 0; b < BB; ++b) dst[b] = v;
    }
}

// ---------------------------------------------------------------------------
// MAIN: fused combine(MFMA bf16, W in f32 C-frags) + apply(VALU f32) + bias.
// Wave = 32 tokens x 4 d x full c. Block = 128 = 2 waves (2 n-halves).
// 1536 blocks = 96 dgrp x 16 ngrp -> 3 waves/SIMD (round-5 was 1.5: latency-bound).
// XCD-chunked bijective swizzle: XCD owns 12 dgrp x 16 ngrp, ngrp-fastest.
// ---------------------------------------------------------------------------
__global__ __launch_bounds__(128, 3) void topo_mfma_kernel(
    const __hip_bfloat16* __restrict__ wfrag,
    const __hip_bfloat16* __restrict__ xfrag,
    const __hip_bfloat16* __restrict__ coefbf,
    float* __restrict__ out) {
    const int tid   = threadIdx.x;
    const int lane  = tid & 63;
    const int nhalf = tid >> 6;
    const int l15   = lane & 15;
    const int g     = lane >> 4;

    const int bid  = blockIdx.x;
    const int xcd  = bid & 7;
    const int slot = bid >> 3;                  // 0..191
    const int dgrp = xcd * 12 + (slot >> 4);    // 0..95  (4 d each)
    const int ngrp = slot & 15;                 // 0..15  (64 n each)

    // coef B-fragments (col = l15 -> token), register-resident
    bf16x8 cf[2][4];
#pragma unroll
    for (int nt = 0; nt < 2; ++nt) {
        const int n = ngrp * 64 + nhalf * 32 + nt * 16 + l15;
#pragma unroll
        for (int kt = 0; kt < 4; ++kt)
            cf[nt][kt] = *reinterpret_cast<const bf16x8*>(coefbf + n * SS + kt * 32 + g * 8);
    }

    f32x4 acc[2][BB];   // [nt][b], components = d_sub 0..3
#pragma unroll
    for (int nt = 0; nt < 2; ++nt)
#pragma unroll
        for (int b = 0; b < BB; ++b) acc[nt][b] = (f32x4){0.f, 0.f, 0.f, 0.f};

    const size_t xgbase = ((size_t)ngrp * 2 + nhalf) * NCQ;
    const bf16x8* abase = reinterpret_cast<const bf16x8*>(wfrag) +
                          ((size_t)dgrp * NCQ * 4) * 64 + lane;

    for (int cq = 0; cq < NCQ; ++cq) {
        bf16x8 xf[2];
#pragma unroll
        for (int nt = 0; nt < 2; ++nt)
            xf[nt] = *reinterpret_cast<const bf16x8*>(
                xfrag + (((xgbase + cq) * 2 + nt) * 64 + lane) * 8);

        const bf16x8* ab = abase + (size_t)cq * 4 * 64;
        const bf16x8 af0 = ab[0];
        const bf16x8 af1 = ab[64];
        const bf16x8 af2 = ab[128];
        const bf16x8 af3 = ab[192];

#pragma unroll
        for (int nt = 0; nt < 2; ++nt) {
            f32x4 wq = (f32x4){0.f, 0.f, 0.f, 0.f};
            wq = __builtin_amdgcn_mfma_f32_16x16x32_bf16(af0, cf[nt][0], wq, 0, 0, 0);
            wq = __builtin_amdgcn_mfma_f32_16x16x32_bf16(af1, cf[nt][1], wq, 0, 0, 0);
            wq = __builtin_amdgcn_mfma_f32_16x16x32_bf16(af2, cf[nt][2], wq, 0, 0, 0);
            wq = __builtin_amdgcn_mfma_f32_16x16x32_bf16(af3, cf[nt][3], wq, 0, 0, 0);
            // wq[r] = W'[n = n0+l15][d = dgrp*4+r][c = cq*4+g]  (bias at cq=96)
#pragma unroll
            for (int b = 0; b < BB; ++b) {
                const float xb = bf2f((unsigned short)xf[nt][b]);
                acc[nt][b] += wq * xb;
            }
        }
    }

    // epilogue: reduce the 4 c-phases (lane groups g) and store
#pragma unroll
    for (int nt = 0; nt < 2; ++nt) {
        const int n = ngrp * 64 + nhalf * 32 + nt * 16 + l15;
        const int dbase = dgrp * 4;
#pragma unroll
        for (int b = 0; b < BB; ++b) {
            f32x4 a = acc[nt][b];
#pragma unroll
            for (int r = 0; r < 4; ++r) {
                float v = a[r];
                v += __shfl_xor(v, 16);
                v += __shfl_xor(v, 32);
                a[r] = v;
            }
            if ((b >> 1) == g) {   // one writer per (b,n,d-quad)
                *reinterpret_cast<f32x4*>(out + ((size_t)b * NN + n) * DOUT + dbase) = a;
            }
        }
    }
}

// ---------------------------------------------------------------------------
extern "C" void kernel_launch(void* const* d_in, const int* in_sizes, int n_in,
                              void* d_out, int out_size, void* d_ws, size_t ws_size,
                              hipStream_t stream) {
    const float* x     = (const float*)d_in[0];   // (8,1024,384)
    const float* pe    = (const float*)d_in[1];   // (1024,128)
    const float* mw    = (const float*)d_in[2];   // (128,128)
    const float* scale = (const float*)d_in[3];   // ()
    const float* wgt   = (const float*)d_in[4];   // (384,384,128)
    const float* bias  = (const float*)d_in[5];   // (384,128)
    float* out = (float*)d_out;

    char* ws = (char*)d_ws;
    float*          wnT    = (float*)(ws + 0);                 //  64 KiB
    __hip_bfloat16* coefbf = (__hip_bfloat16*)(ws + 65536);    // 256 KiB
    __hip_bfloat16* xfrag  = (__hip_bfloat16*)(ws + 327680);   // 6.06 MiB (16*2*97*2*1024 B)
    __hip_bfloat16* wfrag  = (__hip_bfloat16*)(ws + 6684672);  // 36.4 MiB (96*97*4*64*16 B)

    wnorm_kernel<<<dim3(SS), dim3(PP), 0, stream>>>(mw, scale, wnT);
    coef_kernel<<<dim3(NN), dim3(PP), 0, stream>>>(pe, wnT, coefbf);
    xfrag_prep<<<dim3((NN * 388) / 256), dim3(256), 0, stream>>>(x, xfrag);
    wfrag_prep<<<dim3((96 * NCQ * 4 * 64) / 256), dim3(256), 0, stream>>>(wgt, bias, wfrag);
    topo_mfma_kernel<<<dim3(1536), dim3(128), 0, stream>>>(wfrag, xfrag, coefbf, out);
}

// Round 8
// 222.625 us; speedup vs baseline: 12.6977x; 1.0119x over previous
//
#include <hip/hip_runtime.h>
#include <hip/hip_bf16.h>

#define EPSN 1e-12f

// Problem dims
#define BB   8
#define NN   1024
#define DIN  384
#define DOUT 384
#define SS   128
#define PP   128

#define NCQ  97   // 96 weight c-quads + 1 bias (homogeneous) quad

typedef __attribute__((ext_vector_type(8))) short bf16x8;
typedef __attribute__((ext_vector_type(4))) float f32x4;

__device__ __forceinline__ float bf2f(unsigned short u) {
    union { unsigned int i; float f; } v; v.i = ((unsigned int)u) << 16; return v.f;
}

// global -> LDS direct copy, 16B per lane; LDS dst = uniform base + lane*16
#define GLOAD_LDS(gp, lp)                                                            \
    __builtin_amdgcn_global_load_lds(                                                \
        (const __attribute__((address_space(1))) unsigned int*)(gp),                 \
        (__attribute__((address_space(3))) unsigned int*)(lp), 16, 0, 0)

// ---------------------------------------------------------------------------
// prep 1: wnT[p][s] = scale * l2norm(maps_weight)[s][p]  (transposed out)
// ---------------------------------------------------------------------------
__global__ void wnorm_kernel(const float* __restrict__ mw,
                             const float* __restrict__ scale,
                             float* __restrict__ wnT) {
    __shared__ float row[PP];
    const int s = blockIdx.x, t = threadIdx.x;
    row[t] = mw[s * PP + t];
    __syncthreads();
    float ss = 0.f;
#pragma unroll
    for (int p = 0; p < PP; ++p) ss = fmaf(row[p], row[p], ss);
    wnT[t * SS + s] = scale[0] * row[t] / fmaxf(sqrtf(ss), EPSN);
}

// ---------------------------------------------------------------------------
// prep 2: coefbf[n][s] = bf16(softmax_s(l2norm(pe[n]) . wn[s]))
// ---------------------------------------------------------------------------
__global__ void coef_kernel(const float* __restrict__ pe,
                            const float* __restrict__ wnT,
                            __hip_bfloat16* __restrict__ coefbf) {
    __shared__ float pen[PP];
    __shared__ float red[SS];
    const int n = blockIdx.x, t = threadIdx.x;
    pen[t] = pe[n * PP + t];
    __syncthreads();
    float ss = 0.f;
#pragma unroll
    for (int p = 0; p < PP; ++p) ss = fmaf(pen[p], pen[p], ss);
    const float rn = 1.0f / fmaxf(sqrtf(ss), EPSN);
    float lg = 0.f;
#pragma unroll
    for (int p = 0; p < PP; ++p) lg = fmaf(pen[p], wnT[p * SS + t], lg);
    lg *= rn;
    red[t] = lg;
    __syncthreads();
    for (int off = 64; off > 0; off >>= 1) {
        if (t < off) red[t] = fmaxf(red[t], red[t + off]);
        __syncthreads();
    }
    const float m = red[0];
    __syncthreads();
    const float e = expf(lg - m);
    red[t] = e;
    __syncthreads();
    for (int off = 64; off > 0; off >>= 1) {
        if (t < off) red[t] += red[t + off];
        __syncthreads();
    }
    coefbf[n * SS + t] = __float2bfloat16(e / red[0]);
}

// ---------------------------------------------------------------------------
// prep 3: wfrag[dblk 96][cq 97][kt 4][lane 64] x 8 bf16 (bias = cq 96)
// ---------------------------------------------------------------------------
__global__ void wfrag_prep(const float* __restrict__ weight,
                           const float* __restrict__ bias,
                           __hip_bfloat16* __restrict__ wfrag) {
    const int id = blockIdx.x * 256 + threadIdx.x;
    const int lane = id & 63;
    const int kt = (id >> 6) & 3;
    const int rem = id >> 8;
    const int cq = rem % NCQ;
    const int dblk = rem / NCQ;
    const int l15 = lane & 15, g = lane >> 4;
    const int d = dblk * 4 + (l15 & 3);
    const int s0 = kt * 32 + g * 8;
    __hip_bfloat16* dst = wfrag + (size_t)id * 8;
    if (cq < 96) {
        const int c = cq * 4 + (l15 >> 2);
        const float* src = weight + ((size_t)d * DIN + c) * SS + s0;
#pragma unroll
        for (int j = 0; j < 8; ++j) dst[j] = __float2bfloat16(src[j]);
    } else if ((l15 >> 2) == 0) {
        const float* src = bias + (size_t)d * SS + s0;
#pragma unroll
        for (int j = 0; j < 8; ++j) dst[j] = __float2bfloat16(src[j]);
    } else {
#pragma unroll
        for (int j = 0; j < 8; ++j) dst[j] = __float2bfloat16(0.f);
    }
}

// ---------------------------------------------------------------------------
// prep 4: xfrag[(tg 32)*97 + cq)*2 + nt][lane = g*16+l15] x 8 bf16
// ---------------------------------------------------------------------------
__global__ void xfrag_prep(const float* __restrict__ x,
                           __hip_bfloat16* __restrict__ xfrag) {
    const int id = blockIdx.x * 256 + threadIdx.x;    // n*388 + cc
    const int n = id / 388, cc = id % 388;
    const int tg = n >> 5, nt = (n >> 4) & 1, l15 = n & 15;
    const int cq = cc >> 2, g = cc & 3;
    const size_t G = ((size_t)tg * NCQ + cq) * 2 + nt;
    __hip_bfloat16* dst = xfrag + (G * 64 + (g * 16 + l15)) * 8;
    if (cc < 384) {
#pragma unroll
        for (int b = 0; b < BB; ++b)
            dst[b] = __float2bfloat16(x[((size_t)b * NN + n) * DIN + cc]);
    } else {
        const __hip_bfloat16 v = __float2bfloat16(cc == 384 ? 1.0f : 0.0f);
#pragma unroll
        for (int b = 0; b < BB; ++b) dst[b] = v;
    }
}

// ---------------------------------------------------------------------------
// MAIN: 4 waves/block share one dgrp; af staged once/block into LDS dbuf
// (global_load_lds, chunks of 4 cq, stage-next -> compute-current -> barrier).
// Wave = 32 tokens x 4 d x full c. 768 blocks = 96 dgrp x 8 ngrp(128 tok).
// ---------------------------------------------------------------------------
__global__ __launch_bounds__(256, 3) void topo_mfma_kernel(
    const __hip_bfloat16* __restrict__ wfrag,
    const __hip_bfloat16* __restrict__ xfrag,
    const __hip_bfloat16* __restrict__ coefbf,
    float* __restrict__ out) {
    __shared__ __align__(16) char sbuf[2][16384];   // 2 x (4 cq x 4KB)

    const int tid  = threadIdx.x;
    const int lane = tid & 63;
    const int wq   = tid >> 6;          // wave id = token-quarter
    const int l15  = lane & 15;
    const int g    = lane >> 4;

    const int bid  = blockIdx.x;
    const int xcd  = bid & 7;
    const int slot = bid >> 3;                  // 0..95
    const int dgrp = xcd * 12 + (slot >> 3);    // 0..95  (4 d each)
    const int ngrp = slot & 7;                  // 0..7   (128 n each)

    // coef B-fragments, register-resident
    bf16x8 cf[2][4];
#pragma unroll
    for (int nt = 0; nt < 2; ++nt) {
        const int n = ngrp * 128 + wq * 32 + nt * 16 + l15;
#pragma unroll
        for (int kt = 0; kt < 4; ++kt)
            cf[nt][kt] = *reinterpret_cast<const bf16x8*>(coefbf + n * SS + kt * 32 + g * 8);
    }

    f32x4 acc[2][BB];
#pragma unroll
    for (int nt = 0; nt < 2; ++nt)
#pragma unroll
        for (int b = 0; b < BB; ++b) acc[nt][b] = (f32x4){0.f, 0.f, 0.f, 0.f};

    const int tg = ngrp * 4 + wq;               // token-group of 32 (0..31)
    const size_t xgbase = (size_t)tg * NCQ;
    const char* wsrc = (const char*)wfrag + (size_t)dgrp * NCQ * 4096;

    // ---- prologue: stage chunk 0 (cq 0..3) into sbuf[0] ----
#pragma unroll
    for (int k = 0; k < 4; ++k)
        GLOAD_LDS(wsrc + ((size_t)k * 256 + wq * 64 + lane) * 16,
                  sbuf[0] + ((size_t)k * 256 + wq * 64) * 16);
    __syncthreads();

    int par = 0;
    for (int ci = 0; ci < 25; ++ci) {           // 24 chunks of 4 + tail of 1
        const int cq0 = ci * 4;
        const int ncq = (ci == 24) ? 1 : 4;

        // stage next chunk into the other buffer (loads fly during compute)
        if (ci < 24) {
            const int nnext = (ci == 23) ? 1 : 4;
            const char* src = wsrc + (size_t)(cq0 + 4) * 4096;
            char* dst = sbuf[par ^ 1];
#pragma unroll
            for (int k = 0; k < 4; ++k)
                if (k < nnext)
                    GLOAD_LDS(src + ((size_t)k * 256 + wq * 64 + lane) * 16,
                              dst + ((size_t)k * 256 + wq * 64) * 16);
        }

        // compute current chunk from sbuf[par]
        for (int cqs = 0; cqs < ncq; ++cqs) {
            const int cq = cq0 + cqs;
            bf16x8 xf[2];
#pragma unroll
            for (int nt = 0; nt < 2; ++nt)
                xf[nt] = *reinterpret_cast<const bf16x8*>(
                    xfrag + (((xgbase + cq) * 2 + nt) * 64 + lane) * 8);

            const bf16x8* afp =
                reinterpret_cast<const bf16x8*>(sbuf[par] + (size_t)cqs * 4096) + lane;
            const bf16x8 af0 = afp[0];
            const bf16x8 af1 = afp[64];
            const bf16x8 af2 = afp[128];
            const bf16x8 af3 = afp[192];

#pragma unroll
            for (int nt = 0; nt < 2; ++nt) {
                f32x4 wq4 = (f32x4){0.f, 0.f, 0.f, 0.f};
                wq4 = __builtin_amdgcn_mfma_f32_16x16x32_bf16(af0, cf[nt][0], wq4, 0, 0, 0);
                wq4 = __builtin_amdgcn_mfma_f32_16x16x32_bf16(af1, cf[nt][1], wq4, 0, 0, 0);
                wq4 = __builtin_amdgcn_mfma_f32_16x16x32_bf16(af2, cf[nt][2], wq4, 0, 0, 0);
                wq4 = __builtin_amdgcn_mfma_f32_16x16x32_bf16(af3, cf[nt][3], wq4, 0, 0, 0);
                // wq4[r] = W'[n][d = dgrp*4+r][c = cq*4+g]  (bias fold at cq=96)
#pragma unroll
                for (int b = 0; b < BB; ++b) {
                    const float xb = bf2f((unsigned short)xf[nt][b]);
                    acc[nt][b] += wq4 * xb;
                }
            }
        }

        __syncthreads();   // drains vmcnt (stage done) + all readers done
        par ^= 1;
    }

    // epilogue: reduce 4 c-phases (lane groups g) and store
#pragma unroll
    for (int nt = 0; nt < 2; ++nt) {
        const int n = ngrp * 128 + wq * 32 + nt * 16 + l15;
        const int dbase = dgrp * 4;
#pragma unroll
        for (int b = 0; b < BB; ++b) {
            f32x4 a = acc[nt][b];
#pragma unroll
            for (int r = 0; r < 4; ++r) {
                float v = a[r];
                v += __shfl_xor(v, 16);
                v += __shfl_xor(v, 32);
                a[r] = v;
            }
            if ((b >> 1) == g) {   // one writer per (b,n,d-quad)
                *reinterpret_cast<f32x4*>(out + ((size_t)b * NN + n) * DOUT + dbase) = a;
            }
        }
    }
}

// ---------------------------------------------------------------------------
extern "C" void kernel_launch(void* const* d_in, const int* in_sizes, int n_in,
                              void* d_out, int out_size, void* d_ws, size_t ws_size,
                              hipStream_t stream) {
    const float* x     = (const float*)d_in[0];   // (8,1024,384)
    const float* pe    = (const float*)d_in[1];   // (1024,128)
    const float* mw    = (const float*)d_in[2];   // (128,128)
    const float* scale = (const float*)d_in[3];   // ()
    const float* wgt   = (const float*)d_in[4];   // (384,384,128)
    const float* bias  = (const float*)d_in[5];   // (384,128)
    float* out = (float*)d_out;

    char* ws = (char*)d_ws;
    float*          wnT    = (float*)(ws + 0);                 //  64 KiB
    __hip_bfloat16* coefbf = (__hip_bfloat16*)(ws + 65536);    // 256 KiB
    __hip_bfloat16* xfrag  = (__hip_bfloat16*)(ws + 327680);   // 6.06 MiB
    __hip_bfloat16* wfrag  = (__hip_bfloat16*)(ws + 6684672);  // 36.4 MiB

    wnorm_kernel<<<dim3(SS), dim3(PP), 0, stream>>>(mw, scale, wnT);
    coef_kernel<<<dim3(NN), dim3(PP), 0, stream>>>(pe, wnT, coefbf);
    xfrag_prep<<<dim3((NN * 388) / 256), dim3(256), 0, stream>>>(x, xfrag);
    wfrag_prep<<<dim3((96 * NCQ * 4 * 64) / 256), dim3(256), 0, stream>>>(wgt, bias, wfrag);
    topo_mfma_kernel<<<dim3(768), dim3(256), 0, stream>>>(wfrag, xfrag, coefbf, out);
}